// Round 5
// baseline (870.732 us; speedup 1.0000x reference)
//
#include <hip/hip_runtime.h>
#include <hip/hip_fp16.h>
#include <cstddef>

// StackLSTM: T=64, B=128, H=256, L=2.  ops∈{0,1} => stack never pops:
// top-of-stack = h(last push step), maintained by gated update.
//
// Round-12: seq9's measured-best recurrence loop (389us) VERBATIM, plus an
// in-kernel fp32 Xg prologue that computes XgL directly in LDS:
//  * transpose1 + xg_kernel + 32MB Xg ws round-trip DELETED (~135us wall).
//  * Prologue uses the block's (kq,c2) butterfly decomposition: per (t,b)
//    read x[t,b,kq*32..+32] as 8 float4 straight from global (lane-shared ->
//    L1 broadcast; no LDS staging, no barriers), 64 fp32 FMA (b-loop fully
//    unrolled for ILP), 3 shfl_xor rounds, kq==0 writes XgL. ~16K FMA/thread
//    ~= 25-30us at 2 blocks/CU. Numerics identical to old Xg path
//    (x@Wih0 + b_ih0 in fp32; b_hh0 still added via gatA).
//  * r10/r11 lesson: 2 blocks/CU co-residency is the latency hider for the
//    exchange RTs — keep 512 blocks, launch_bounds(256,2), 4 b per block.
//  * ws now only holds the two tagged exchange rings (524KB).
#define TT 64
#define BB 128
#define HH 256
#define G4 1024
#define BLK 256
#define NBG 32

// ws float-slot offsets
#define OFF_HX0 0u        // u64 [2 par][32 bg][4 b][128 k2] = 65,536 floats
#define OFF_HX1 65536u    // same

__device__ __forceinline__ float sigf(float x) { return 1.0f / (1.0f + expf(-x)); }

typedef _Float16 h2v __attribute__((ext_vector_type(2)));

__device__ __forceinline__ float dot2acc(unsigned w, unsigned h, float acc) {
#if __has_builtin(__builtin_amdgcn_fdot2)
  return __builtin_amdgcn_fdot2(__builtin_bit_cast(h2v, w),
                                __builtin_bit_cast(h2v, h), acc, false);
#else
  __half2 wv = *(__half2*)&w, hv = *(__half2*)&h;
  float2 wf = __half22float2(wv), hf = __half22float2(hv);
  return fmaf(wf.x, hf.x, fmaf(wf.y, hf.y, acc));
#endif
}

__device__ __forceinline__ unsigned packh2(float e, float o) {
  return (unsigned)__half_as_ushort(__float2half(e)) |
         ((unsigned)__half_as_ushort(__float2half(o)) << 16);
}

// swizzled word offset in the [4][144] h-buffers: row kq (16 words) staggered
// by (kq>>1)*4 words so the 8 row starts hit banks {0,16,4,20,8,24,12,28}.
__device__ __forceinline__ int hsw(int b, int k2) {
  return b * 144 + k2 + ((k2 >> 5) << 2);
}

__global__ void __launch_bounds__(BLK, 2)
seq12(const float* __restrict__ x,
      const int* __restrict__ ops,
      const float* __restrict__ W_ih,
      const float* __restrict__ W_hh,
      const float* __restrict__ b_ih,
      const float* __restrict__ b_hh,
      float* __restrict__ ws,
      float* __restrict__ out) {
  const int bg = blockIdx.x & 31;     // batch group (4 b); group = same bg
  const int hg = blockIdx.x >> 5;     // 0..15
  const int tid = threadIdx.x;
  const int kq = tid & 7;             // k-slice: k2 in [kq*16, kq*16+16)
  const int c2 = tid >> 3;            // 0..31: cols {c2*2, c2*2+1}

  __shared__ __align__(16) float XgL[TT * 256];   // 64 KB [t][b][lc]
  __shared__ __align__(16) unsigned hp0[4 * 144]; // swizzled gated h0 (f16x2)
  __shared__ __align__(16) unsigned hp1[4 * 144]; // swizzled gated h1
  __shared__ __align__(16) unsigned h0c[4 * 144]; // swizzled raw h0(t)
  __shared__ float gatA[256];         // [4 b][64 lc] layer-0 gates
  __shared__ float gatB[256];         // layer-1 gates
  __shared__ int opsA[TT * 4];        // [t][b]

  for (int i = tid; i < TT * 4; i += BLK)
    opsA[i] = ops[(i >> 2) * BB + bg * 4 + (i & 3)];
  for (int i = tid; i < 4 * 144; i += BLK) { hp0[i] = 0u; hp1[i] = 0u; }

  // ---- prologue A: in-LDS Xg compute (fp32 exact, butterfly over kq) ----
  {
    float wx0[64], pb0[2];
#pragma unroll
    for (int j = 0; j < 2; ++j) {
      const int lc = c2 * 2 + j;
      const int g = ((lc >> 4) << 8) + hg * 16 + (lc & 15);
      const float* pw = W_ih + (size_t)g * HH + kq * 32;
#pragma unroll
      for (int i = 0; i < 32; ++i) wx0[j * 32 + i] = pw[i];
      pb0[j] = b_ih[g];               // b_hh0 stays in the gatA path (seq9)
    }
    for (int t = 0; t < TT; ++t) {
#pragma unroll
      for (int b = 0; b < 4; ++b) {
        const float* xp = x + ((size_t)t * BB + bg * 4 + b) * HH + kq * 32;
        float s0 = 0.f, s1 = 0.f;
#pragma unroll
        for (int k = 0; k < 32; k += 4) {
          const float4 xv = *(const float4*)(xp + k);
          s0 = fmaf(wx0[k], xv.x, s0);
          s0 = fmaf(wx0[k + 1], xv.y, s0);
          s0 = fmaf(wx0[k + 2], xv.z, s0);
          s0 = fmaf(wx0[k + 3], xv.w, s0);
          s1 = fmaf(wx0[32 + k], xv.x, s1);
          s1 = fmaf(wx0[32 + k + 1], xv.y, s1);
          s1 = fmaf(wx0[32 + k + 2], xv.z, s1);
          s1 = fmaf(wx0[32 + k + 3], xv.w, s1);
        }
#pragma unroll
        for (int m = 1; m <= 4; m <<= 1) {
          s0 += __shfl_xor(s0, m, 64);
          s1 += __shfl_xor(s1, m, 64);
        }
        if (kq == 0)
          *(float2*)&XgL[t * 256 + b * 64 + c2 * 2] =
              make_float2(s0 + pb0[0], s1 + pb0[1]);
      }
    }
  }

  // ---- prologue B: recurrence weights -> VGPRs (f16 pairs) ----
  unsigned wr0[32], wr1[32], wr2[32];
  {
    const float* s0 = W_hh;                       // W_hh[0]
    const float* s1 = W_ih + (size_t)G4 * HH;     // W_ih[1]
    const float* s2 = W_hh + (size_t)G4 * HH;     // W_hh[1]
#pragma unroll
    for (int j = 0; j < 2; ++j) {
      const int lc = c2 * 2 + j;
      const int g = ((lc >> 4) << 8) + hg * 16 + (lc & 15);
      const float* p0 = s0 + (size_t)g * HH + kq * 32;
      const float* p1 = s1 + (size_t)g * HH + kq * 32;
      const float* p2 = s2 + (size_t)g * HH + kq * 32;
#pragma unroll
      for (int i = 0; i < 16; ++i) {
        wr0[j * 16 + i] = packh2(p0[2 * i], p0[2 * i + 1]);
        wr1[j * 16 + i] = packh2(p1[2 * i], p1[2 * i + 1]);
        wr2[j * 16 + i] = packh2(p2[2 * i], p2[2 * i + 1]);
      }
    }
  }
  float bias0r[2], bias1r[2];
#pragma unroll
  for (int j = 0; j < 2; ++j) {
    const int lc = c2 * 2 + j;
    const int g = ((lc >> 4) << 8) + hg * 16 + (lc & 15);
    bias0r[j] = b_hh[g];                           // b_ih0 folded into XgL
    bias1r[j] = b_ih[G4 + g] + b_hh[G4 + g];
  }

  unsigned long long* __restrict__ Hx0 = (unsigned long long*)(ws + OFF_HX0);
  unsigned long long* __restrict__ Hx1 = (unsigned long long*)(ws + OFF_HX1);
  float cp0 = 0.f, cp1 = 0.f;         // cell state, held by tid<64
  // push-gated caches: post-butterfly sums (valid in ALL lanes)
  float a0r[4][2] = {{0.f, 0.f}, {0.f, 0.f}, {0.f, 0.f}, {0.f, 0.f}};
  float a1q[4][2] = {{0.f, 0.f}, {0.f, 0.f}, {0.f, 0.f}, {0.f, 0.f}};
  __syncthreads();   // covers XgL writes, hp0/hp1 init, opsA

  for (int t = 0; t < TT; ++t) {
    const int par = t & 1;

    // ---- layer-0 dots: recompute wr0.hp0 only for b pushed at t-1 ----
#pragma unroll
    for (int b = 0; b < 4; ++b) {
      if (t > 0 && opsA[(t - 1) * 4 + b]) {        // uniform branch
        const unsigned* hb = &hp0[b * 144 + kq * 16 + ((kq >> 1) << 2)];
        const uint4 x0 = *(const uint4*)(hb + 0);
        const uint4 x1 = *(const uint4*)(hb + 4);
        const uint4 x2 = *(const uint4*)(hb + 8);
        const uint4 x3 = *(const uint4*)(hb + 12);
        const unsigned hh[16] = {x0.x, x0.y, x0.z, x0.w, x1.x, x1.y, x1.z, x1.w,
                                 x2.x, x2.y, x2.z, x2.w, x3.x, x3.y, x3.z, x3.w};
        float s0 = 0.f, s1 = 0.f;
#pragma unroll
        for (int i = 0; i < 16; ++i) {
          s0 = dot2acc(wr0[i], hh[i], s0);
          s1 = dot2acc(wr0[16 + i], hh[i], s1);
        }
#pragma unroll
        for (int m = 1; m <= 4; m <<= 1) {
          s0 += __shfl_xor(s0, m, 64);
          s1 += __shfl_xor(s1, m, 64);
        }
        a0r[b][0] = s0;
        a0r[b][1] = s1;
      }
    }
    if (kq == 0) {
#pragma unroll
      for (int b = 0; b < 4; ++b)
        *(float2*)&gatA[b * 64 + c2 * 2] =
            make_float2(a0r[b][0] + bias0r[0], a0r[b][1] + bias0r[1]);
    }
    __syncthreads();  // B1: gatA ready; also orders hp0 reads before merge

    // ---- cell 0 + tagged publish of h0 (8-B relaxed atomics) ----
    if (tid < 64) {
      const int b = tid >> 4, r = tid & 15;
      const float* xg = &XgL[t * 256 + b * 64];
      const float* gt = &gatA[b * 64];
      const float ig = gt[r] + xg[r],           fg = gt[16 + r] + xg[16 + r];
      const float gg = gt[32 + r] + xg[32 + r], og = gt[48 + r] + xg[48 + r];
      const float c = sigf(fg) * cp0 + sigf(ig) * tanhf(gg);
      const float h = sigf(og) * tanhf(c);
      if (opsA[t * 4 + b]) cp0 = c;
      const float ho = __shfl_xor(h, 1, 64);  // pair partner (wave 0 full)
      if (!(r & 1)) {
        const unsigned long long v =
            (unsigned long long)(unsigned)(t + 1) |
            ((unsigned long long)packh2(h, ho) << 32);
        __hip_atomic_store(
            Hx0 + ((size_t)par * NBG + bg) * 512 + b * 128 + hg * 8 + (r >> 1),
            v, __ATOMIC_RELAXED, __HIP_MEMORY_SCOPE_AGENT);
      }
    }
    // no sync: merge polls below self-synchronize on the tags

    // ---- merge: ONE combined spin over all needed words (overlapped RTs) --
    {
      const unsigned long long* s0 = Hx0 + ((size_t)par * NBG + bg) * 512;
      const unsigned long long* s1 = Hx1 + ((size_t)(par ^ 1) * NBG + bg) * 512;
      const unsigned tagA = (unsigned)(t + 1);
      const unsigned tagB = (unsigned)t;
      const int idx1 = tid + 256;
      const int b0 = tid >> 7, k20 = tid & 127;
      const int b1 = idx1 >> 7, k21 = idx1 & 127;
      const bool need1a = (t > 0) && (opsA[(t - 1) * 4 + b0] != 0);
      const bool need1b = (t > 0) && (opsA[(t - 1) * 4 + b1] != 0);
      unsigned long long v0 = 0, v1 = 0, w0 = 0, w1 = 0;
      bool d0 = false, d1 = false, e0 = !need1a, e1 = !need1b;
      int spins = 0;
      for (;;) {
        // issue ALL unresolved loads back-to-back so their latencies overlap
        if (!d0) v0 = __hip_atomic_load(s0 + tid, __ATOMIC_RELAXED,
                                        __HIP_MEMORY_SCOPE_AGENT);
        if (!d1) v1 = __hip_atomic_load(s0 + idx1, __ATOMIC_RELAXED,
                                        __HIP_MEMORY_SCOPE_AGENT);
        if (!e0) w0 = __hip_atomic_load(s1 + tid, __ATOMIC_RELAXED,
                                        __HIP_MEMORY_SCOPE_AGENT);
        if (!e1) w1 = __hip_atomic_load(s1 + idx1, __ATOMIC_RELAXED,
                                        __HIP_MEMORY_SCOPE_AGENT);
        d0 = d0 || ((unsigned)v0 == tagA);
        d1 = d1 || ((unsigned)v1 == tagA);
        e0 = e0 || ((unsigned)w0 == tagB);
        e1 = e1 || ((unsigned)w1 == tagB);
        if (d0 && d1 && e0 && e1) break;
        if (++spins > (1 << 18)) break;  // fail loudly instead of hanging
        if (spins > 2) __builtin_amdgcn_s_sleep(1);
      }
      const unsigned p0 = (unsigned)(v0 >> 32), p1 = (unsigned)(v1 >> 32);
      const int sw0 = hsw(b0, k20), sw1 = hsw(b1, k21);
      h0c[sw0] = p0;
      h0c[sw1] = p1;
      if (opsA[t * 4 + b0]) hp0[sw0] = p0;
      if (opsA[t * 4 + b1]) hp0[sw1] = p1;
      if (need1a) hp1[sw0] = (unsigned)(w0 >> 32);
      if (need1b) hp1[sw1] = (unsigned)(w1 >> 32);
    }
    __syncthreads();  // B2: h0c/hp0/hp1 ready for layer-1 reads

    // ---- layer-1 dots: wr1.h0c every step; wr2.hp1 only on push ----
    float fr[4][2];
#pragma unroll
    for (int b = 0; b < 4; ++b) {
      const unsigned* cb = &h0c[b * 144 + kq * 16 + ((kq >> 1) << 2)];
      const uint4 c0 = *(const uint4*)(cb + 0);
      const uint4 c1 = *(const uint4*)(cb + 4);
      const uint4 c2v = *(const uint4*)(cb + 8);
      const uint4 c3 = *(const uint4*)(cb + 12);
      const unsigned hc[16] = {c0.x, c0.y, c0.z, c0.w, c1.x, c1.y, c1.z, c1.w,
                               c2v.x, c2v.y, c2v.z, c2v.w, c3.x, c3.y, c3.z, c3.w};
      float s0 = 0.f, s1 = 0.f;
#pragma unroll
      for (int i = 0; i < 16; ++i) {
        s0 = dot2acc(wr1[i], hc[i], s0);
        s1 = dot2acc(wr1[16 + i], hc[i], s1);
      }
      if (t > 0 && opsA[(t - 1) * 4 + b]) {        // uniform branch
        const unsigned* qb = &hp1[b * 144 + kq * 16 + ((kq >> 1) << 2)];
        const uint4 q0 = *(const uint4*)(qb + 0);
        const uint4 q1 = *(const uint4*)(qb + 4);
        const uint4 q2 = *(const uint4*)(qb + 8);
        const uint4 q3 = *(const uint4*)(qb + 12);
        const unsigned hq[16] = {q0.x, q0.y, q0.z, q0.w, q1.x, q1.y, q1.z, q1.w,
                                 q2.x, q2.y, q2.z, q2.w, q3.x, q3.y, q3.z, q3.w};
        float t0 = 0.f, t1 = 0.f;
#pragma unroll
        for (int i = 0; i < 16; ++i) {
          t0 = dot2acc(wr2[i], hq[i], t0);
          t1 = dot2acc(wr2[16 + i], hq[i], t1);
        }
#pragma unroll
        for (int m = 1; m <= 4; m <<= 1) {
          t0 += __shfl_xor(t0, m, 64);
          t1 += __shfl_xor(t1, m, 64);
        }
        a1q[b][0] = t0;
        a1q[b][1] = t1;
      }
#pragma unroll
      for (int m = 1; m <= 4; m <<= 1) {
        s0 += __shfl_xor(s0, m, 64);
        s1 += __shfl_xor(s1, m, 64);
      }
      fr[b][0] = s0;
      fr[b][1] = s1;
    }
    if (kq == 0) {
#pragma unroll
      for (int b = 0; b < 4; ++b)
        *(float2*)&gatB[b * 64 + c2 * 2] =
            make_float2(fr[b][0] + a1q[b][0] + bias1r[0],
                        fr[b][1] + a1q[b][1] + bias1r[1]);
    }
    __syncthreads();  // B3: gatB ready

    // ---- cell 1: output + gated tagged publish of h1 ----
    if (tid < 64) {
      const int b = tid >> 4, r = tid & 15;
      const float* gt = &gatB[b * 64];
      const float ig = gt[r],      fg = gt[16 + r];
      const float gg = gt[32 + r], og = gt[48 + r];
      const float c = sigf(fg) * cp1 + sigf(ig) * tanhf(gg);
      const float h = sigf(og) * tanhf(c);
      const int op = opsA[t * 4 + b];
      if (op) cp1 = c;
      out[((size_t)t * BB + bg * 4 + b) * HH + hg * 16 + r] = h;
      const float ho = __shfl_xor(h, 1, 64);
      if (op && !(r & 1)) {  // consumers poll this word only when op=1
        const unsigned long long v =
            (unsigned long long)(unsigned)(t + 1) |
            ((unsigned long long)packh2(h, ho) << 32);
        __hip_atomic_store(
            Hx1 + ((size_t)par * NBG + bg) * 512 + b * 128 + hg * 8 + (r >> 1),
            v, __ATOMIC_RELAXED, __HIP_MEMORY_SCOPE_AGENT);
      }
    }
    // no trailing barrier: gatA/gatB split + B1/B2 of next step cover reuse
  }
}

// ---------------------------------------------------------------------------
extern "C" void kernel_launch(void* const* d_in, const int* in_sizes, int n_in,
                              void* d_out, int out_size, void* d_ws, size_t ws_size,
                              hipStream_t stream) {
  const float* x    = (const float*)d_in[0];
  const int*   ops  = (const int*)d_in[1];
  const float* W_ih = (const float*)d_in[2];
  const float* W_hh = (const float*)d_in[3];
  const float* b_ih = (const float*)d_in[4];
  const float* b_hh = (const float*)d_in[5];
  float* out = (float*)d_out;
  float* ws  = (float*)d_ws;

  seq12<<<512, BLK, 0, stream>>>(x, ops, W_ih, W_hh, b_ih, b_hh, ws, out);
}

// Round 6
// 487.775 us; speedup vs baseline: 1.7851x; 1.7851x over previous
//
#include <hip/hip_runtime.h>
#include <hip/hip_fp16.h>
#include <cstddef>

// StackLSTM: T=64, B=128, H=256, L=2.  ops∈{0,1} => stack never pops:
// top-of-stack = h(last push step), maintained by gated update.
//
// Round-13: r9's two-part structure restored (it is the measured best:
// seq9 = 389us, entered ALIGNED — r11/r12 proved any variable-latency
// prologue before the lockstep poll loop triggers straggler collapse).
//  * Front-end replaced: transpose1 + xg_kernel (~125-135us) -> ONE
//    register-tiled fp32 GEMM (128x128 tile, 8x8 acc/thread, W read
//    directly, bias folded, writes seq9's [t][hg][b][lc] layout).
//    4.3 GFLOP at fp32 vector peak = 27us; predicted 35-55us.
//  * seq9 recurrence kernel VERBATIM from the 389us run; only ws offset
//    macros moved (rings at 0, Xg at 131072 floats). 34MB ws total.
#define TT 64
#define BB 128
#define HH 256
#define G4 1024
#define BLK 256
#define NBG 32

// ws float-slot offsets
#define OFF_HX0 0u         // u64 [2 par][32 bg][4 b][128 k2] = 65,536 floats
#define OFF_HX1 65536u     // same
#define OFF_XG  131072u    // [64 t][16 hg][128 b][64 lc] fp32 = 8,388,608
// total 8,519,680 floats = 34.1 MB (< proven 35.1 MB budget)

__device__ __forceinline__ float sigf(float x) { return 1.0f / (1.0f + expf(-x)); }

typedef _Float16 h2v __attribute__((ext_vector_type(2)));

__device__ __forceinline__ float dot2acc(unsigned w, unsigned h, float acc) {
#if __has_builtin(__builtin_amdgcn_fdot2)
  return __builtin_amdgcn_fdot2(__builtin_bit_cast(h2v, w),
                                __builtin_bit_cast(h2v, h), acc, false);
#else
  __half2 wv = *(__half2*)&w, hv = *(__half2*)&h;
  float2 wf = __half22float2(wv), hf = __half22float2(hv);
  return fmaf(wf.x, hf.x, fmaf(wf.y, hf.y, acc));
#endif
}

__device__ __forceinline__ unsigned packh2(float e, float o) {
  return (unsigned)__half_as_ushort(__float2half(e)) |
         ((unsigned)__half_as_ushort(__float2half(o)) << 16);
}

// swizzled word offset in the [4][144] h-buffers: row kq (16 words) staggered
// by (kq>>1)*4 words so the 8 row starts hit banks {0,16,4,20,8,24,12,28}.
__device__ __forceinline__ int hsw(int b, int k2) {
  return b * 144 + k2 + ((k2 >> 5) << 2);
}

// ---------------------------------------------------------------------------
// xg_gemm: Xg[t][hg][b][lc] = x[t,b,:] @ W_ih0[g,:] + b_ih0[g]   (fp32 exact)
// C[m=t*128+b][g], M=8192, N=1024, K=256.  128x128 tile, 8x8 per thread.
// g mapping: hg=(g>>4)&15, lc=((g>>8)<<4)|(g&15)  (matches seq9's reader).
// ---------------------------------------------------------------------------
__global__ void __launch_bounds__(256, 2)
xg_gemm(const float* __restrict__ X,      // [8192][256] (x viewed flat)
        const float* __restrict__ W,      // [1024][256] = W_ih[0]
        const float* __restrict__ bias,   // b_ih layer 0 (first 1024)
        float* __restrict__ ws) {
  float* __restrict__ Xg = ws + OFF_XG;
  const int m0 = blockIdx.x * 128;      // 64 row tiles (t = blockIdx.x)
  const int n0 = blockIdx.y * 128;      // 8 col tiles
  const int tid = threadIdx.x;
  const int tx = tid & 15, ty = tid >> 4;

  __shared__ __align__(16) float Xs[32][132];   // [k][row], +4 pad
  __shared__ __align__(16) float Wn[32][132];   // [k][col], +4 pad

  // staging: thread owns row lr, k-halves lk..lk+16 (64B contiguous)
  const int lr = tid >> 1, lk = (tid & 1) * 16;
  const float* xrow = X + (size_t)(m0 + lr) * HH + lk;
  const float* wrow = W + (size_t)(n0 + lr) * HH + lk;

  float acc[8][8];
#pragma unroll
  for (int i = 0; i < 8; ++i)
#pragma unroll
    for (int j = 0; j < 8; ++j) acc[i][j] = 0.f;

  float4 xr[4], wr[4];
#pragma unroll
  for (int q = 0; q < 4; ++q) {
    xr[q] = *(const float4*)(xrow + q * 4);
    wr[q] = *(const float4*)(wrow + q * 4);
  }

  for (int ks = 0; ks < 8; ++ks) {
    // regs -> LDS (transposed). 2-way write conflicts only (free).
#pragma unroll
    for (int q = 0; q < 4; ++q) {
      Xs[lk + q * 4 + 0][lr] = xr[q].x;
      Xs[lk + q * 4 + 1][lr] = xr[q].y;
      Xs[lk + q * 4 + 2][lr] = xr[q].z;
      Xs[lk + q * 4 + 3][lr] = xr[q].w;
      Wn[lk + q * 4 + 0][lr] = wr[q].x;
      Wn[lk + q * 4 + 1][lr] = wr[q].y;
      Wn[lk + q * 4 + 2][lr] = wr[q].z;
      Wn[lk + q * 4 + 3][lr] = wr[q].w;
    }
    __syncthreads();
    if (ks < 7) {   // prefetch next k-slab while computing this one
      const float* xn = xrow + (ks + 1) * 32;
      const float* wn = wrow + (ks + 1) * 32;
#pragma unroll
      for (int q = 0; q < 4; ++q) {
        xr[q] = *(const float4*)(xn + q * 4);
        wr[q] = *(const float4*)(wn + q * 4);
      }
    }
#pragma unroll 8
    for (int k = 0; k < 32; ++k) {
      // rows: broadcast (4 distinct ty/wave); cols: stride-4 pairs (2-way)
      const float4 a0 = *(const float4*)&Xs[k][ty * 8];
      const float4 a1 = *(const float4*)&Xs[k][ty * 8 + 4];
      const float4 b0 = *(const float4*)&Wn[k][tx * 4];
      const float4 b1 = *(const float4*)&Wn[k][64 + tx * 4];
      const float ar[8] = {a0.x, a0.y, a0.z, a0.w, a1.x, a1.y, a1.z, a1.w};
      const float br[8] = {b0.x, b0.y, b0.z, b0.w, b1.x, b1.y, b1.z, b1.w};
#pragma unroll
      for (int i = 0; i < 8; ++i)
#pragma unroll
        for (int j = 0; j < 8; ++j) acc[i][j] = fmaf(ar[i], br[j], acc[i][j]);
    }
    __syncthreads();
  }

  // epilogue: +bias, scatter to seq9's [t][hg][b][lc] layout (float4 runs)
  const int t = m0 >> 7;
#pragma unroll
  for (int h = 0; h < 2; ++h) {
    const int base = n0 + h * 64 + tx * 4;            // global col of 4-run
    const int hg = (base >> 4) & 15;
    const int lc = ((base >> 8) << 4) | (base & 15);
    const float4 bv = *(const float4*)(bias + base);
#pragma unroll
    for (int i = 0; i < 8; ++i) {
      const int b = ty * 8 + i;
      float4 v;
      v.x = acc[i][h * 4 + 0] + bv.x;
      v.y = acc[i][h * 4 + 1] + bv.y;
      v.z = acc[i][h * 4 + 2] + bv.z;
      v.w = acc[i][h * 4 + 3] + bv.w;
      *(float4*)&Xg[(((size_t)t * 16 + hg) * 128 + b) * 64 + lc] = v;
    }
  }
}

// ---------------------------------------------------------------------------
// Sequential recurrence: register weights + tagged dataflow exchange.
// VERBATIM the 389us seq9 (round-2); only ws offset macros differ.
// ---------------------------------------------------------------------------
__global__ void __launch_bounds__(BLK, 2)
seq9(const float* __restrict__ W_ih,
     const float* __restrict__ W_hh,
     const float* __restrict__ b_ih,
     const float* __restrict__ b_hh,
     const int* __restrict__ ops,
     float* __restrict__ ws,
     float* __restrict__ out) {
  const int bg = blockIdx.x & 31;     // batch group (4 b); group = same bg
  const int hg = blockIdx.x >> 5;     // 0..15
  const int tid = threadIdx.x;
  const int kq = tid & 7;             // k-slice: k2 in [kq*16, kq*16+16)
  const int c2 = tid >> 3;            // 0..31: cols {c2*2, c2*2+1}

  __shared__ __align__(16) float XgL[TT * 256];   // 64 KB [t][b][lc]
  __shared__ __align__(16) unsigned hp0[4 * 144]; // swizzled gated h0 (f16x2)
  __shared__ __align__(16) unsigned hp1[4 * 144]; // swizzled gated h1
  __shared__ __align__(16) unsigned h0c[4 * 144]; // swizzled raw h0(t)
  __shared__ float gatA[256];         // [4 b][64 lc] layer-0 gates
  __shared__ float gatB[256];         // layer-1 gates
  __shared__ int opsA[TT * 4];        // [t][b]

  // ---- prologue: weights -> VGPRs (f16 pairs), Xg slice -> LDS ----
  unsigned wr0[32], wr1[32], wr2[32];
  {
    const float* s0 = W_hh;                       // W_hh[0]
    const float* s1 = W_ih + (size_t)G4 * HH;     // W_ih[1]
    const float* s2 = W_hh + (size_t)G4 * HH;     // W_hh[1]
#pragma unroll
    for (int j = 0; j < 2; ++j) {
      const int lc = c2 * 2 + j;
      const int g = ((lc >> 4) << 8) + hg * 16 + (lc & 15);
      const float* p0 = s0 + (size_t)g * HH + kq * 32;
      const float* p1 = s1 + (size_t)g * HH + kq * 32;
      const float* p2 = s2 + (size_t)g * HH + kq * 32;
#pragma unroll
      for (int i = 0; i < 16; ++i) {
        wr0[j * 16 + i] = packh2(p0[2 * i], p0[2 * i + 1]);
        wr1[j * 16 + i] = packh2(p1[2 * i], p1[2 * i + 1]);
        wr2[j * 16 + i] = packh2(p2[2 * i], p2[2 * i + 1]);
      }
    }
  }
  float bias0r[2], bias1r[2];
#pragma unroll
  for (int j = 0; j < 2; ++j) {
    const int lc = c2 * 2 + j;
    const int g = ((lc >> 4) << 8) + hg * 16 + (lc & 15);
    bias0r[j] = b_hh[g];                           // b_ih0 folded into Xg
    bias1r[j] = b_ih[G4 + g] + b_hh[G4 + g];
  }
  for (int i = tid; i < TT * 64; i += BLK) {       // 4096 float4
    const int t = i >> 6, r = i & 63;
    ((float4*)XgL)[i] = *(const float4*)(
        ws + OFF_XG + (((size_t)t * 16 + hg) * 128 + bg * 4) * 64 + r * 4);
  }
  for (int i = tid; i < TT * 4; i += BLK)
    opsA[i] = ops[(i >> 2) * BB + bg * 4 + (i & 3)];
  for (int i = tid; i < 4 * 144; i += BLK) { hp0[i] = 0u; hp1[i] = 0u; }

  unsigned long long* __restrict__ Hx0 = (unsigned long long*)(ws + OFF_HX0);
  unsigned long long* __restrict__ Hx1 = (unsigned long long*)(ws + OFF_HX1);
  float cp0 = 0.f, cp1 = 0.f;         // cell state, held by tid<64
  // push-gated caches: post-butterfly sums (valid in ALL lanes)
  float a0r[4][2] = {{0.f, 0.f}, {0.f, 0.f}, {0.f, 0.f}, {0.f, 0.f}};
  float a1q[4][2] = {{0.f, 0.f}, {0.f, 0.f}, {0.f, 0.f}, {0.f, 0.f}};
  __syncthreads();

  for (int t = 0; t < TT; ++t) {
    const int par = t & 1;

    // ---- layer-0 dots: recompute wr0.hp0 only for b pushed at t-1 ----
#pragma unroll
    for (int b = 0; b < 4; ++b) {
      if (t > 0 && opsA[(t - 1) * 4 + b]) {        // uniform branch
        const unsigned* hb = &hp0[b * 144 + kq * 16 + ((kq >> 1) << 2)];
        const uint4 x0 = *(const uint4*)(hb + 0);
        const uint4 x1 = *(const uint4*)(hb + 4);
        const uint4 x2 = *(const uint4*)(hb + 8);
        const uint4 x3 = *(const uint4*)(hb + 12);
        const unsigned hh[16] = {x0.x, x0.y, x0.z, x0.w, x1.x, x1.y, x1.z, x1.w,
                                 x2.x, x2.y, x2.z, x2.w, x3.x, x3.y, x3.z, x3.w};
        float s0 = 0.f, s1 = 0.f;
#pragma unroll
        for (int i = 0; i < 16; ++i) {
          s0 = dot2acc(wr0[i], hh[i], s0);
          s1 = dot2acc(wr0[16 + i], hh[i], s1);
        }
#pragma unroll
        for (int m = 1; m <= 4; m <<= 1) {
          s0 += __shfl_xor(s0, m, 64);
          s1 += __shfl_xor(s1, m, 64);
        }
        a0r[b][0] = s0;
        a0r[b][1] = s1;
      }
    }
    if (kq == 0) {
#pragma unroll
      for (int b = 0; b < 4; ++b)
        *(float2*)&gatA[b * 64 + c2 * 2] =
            make_float2(a0r[b][0] + bias0r[0], a0r[b][1] + bias0r[1]);
    }
    __syncthreads();  // B1: gatA ready; also orders hp0 reads before merge

    // ---- cell 0 + tagged publish of h0 (8-B relaxed atomics) ----
    if (tid < 64) {
      const int b = tid >> 4, r = tid & 15;
      const float* xg = &XgL[t * 256 + b * 64];
      const float* gt = &gatA[b * 64];
      const float ig = gt[r] + xg[r],           fg = gt[16 + r] + xg[16 + r];
      const float gg = gt[32 + r] + xg[32 + r], og = gt[48 + r] + xg[48 + r];
      const float c = sigf(fg) * cp0 + sigf(ig) * tanhf(gg);
      const float h = sigf(og) * tanhf(c);
      if (opsA[t * 4 + b]) cp0 = c;
      const float ho = __shfl_xor(h, 1, 64);  // pair partner (wave 0 full)
      if (!(r & 1)) {
        const unsigned long long v =
            (unsigned long long)(unsigned)(t + 1) |
            ((unsigned long long)packh2(h, ho) << 32);
        __hip_atomic_store(
            Hx0 + ((size_t)par * NBG + bg) * 512 + b * 128 + hg * 8 + (r >> 1),
            v, __ATOMIC_RELAXED, __HIP_MEMORY_SCOPE_AGENT);
      }
    }
    // no sync: merge polls below self-synchronize on the tags

    // ---- merge: ONE combined spin over all needed words (overlapped RTs) --
    {
      const unsigned long long* s0 = Hx0 + ((size_t)par * NBG + bg) * 512;
      const unsigned long long* s1 = Hx1 + ((size_t)(par ^ 1) * NBG + bg) * 512;
      const unsigned tagA = (unsigned)(t + 1);
      const unsigned tagB = (unsigned)t;
      const int idx1 = tid + 256;
      const int b0 = tid >> 7, k20 = tid & 127;
      const int b1 = idx1 >> 7, k21 = idx1 & 127;
      const bool need1a = (t > 0) && (opsA[(t - 1) * 4 + b0] != 0);
      const bool need1b = (t > 0) && (opsA[(t - 1) * 4 + b1] != 0);
      unsigned long long v0 = 0, v1 = 0, w0 = 0, w1 = 0;
      bool d0 = false, d1 = false, e0 = !need1a, e1 = !need1b;
      int spins = 0;
      for (;;) {
        // issue ALL unresolved loads back-to-back so their latencies overlap
        if (!d0) v0 = __hip_atomic_load(s0 + tid, __ATOMIC_RELAXED,
                                        __HIP_MEMORY_SCOPE_AGENT);
        if (!d1) v1 = __hip_atomic_load(s0 + idx1, __ATOMIC_RELAXED,
                                        __HIP_MEMORY_SCOPE_AGENT);
        if (!e0) w0 = __hip_atomic_load(s1 + tid, __ATOMIC_RELAXED,
                                        __HIP_MEMORY_SCOPE_AGENT);
        if (!e1) w1 = __hip_atomic_load(s1 + idx1, __ATOMIC_RELAXED,
                                        __HIP_MEMORY_SCOPE_AGENT);
        d0 = d0 || ((unsigned)v0 == tagA);
        d1 = d1 || ((unsigned)v1 == tagA);
        e0 = e0 || ((unsigned)w0 == tagB);
        e1 = e1 || ((unsigned)w1 == tagB);
        if (d0 && d1 && e0 && e1) break;
        if (++spins > (1 << 18)) break;  // fail loudly instead of hanging
        if (spins > 2) __builtin_amdgcn_s_sleep(1);
      }
      const unsigned p0 = (unsigned)(v0 >> 32), p1 = (unsigned)(v1 >> 32);
      const int sw0 = hsw(b0, k20), sw1 = hsw(b1, k21);
      h0c[sw0] = p0;
      h0c[sw1] = p1;
      if (opsA[t * 4 + b0]) hp0[sw0] = p0;
      if (opsA[t * 4 + b1]) hp0[sw1] = p1;
      if (need1a) hp1[sw0] = (unsigned)(w0 >> 32);
      if (need1b) hp1[sw1] = (unsigned)(w1 >> 32);
    }
    __syncthreads();  // B2: h0c/hp0/hp1 ready for layer-1 reads

    // ---- layer-1 dots: wr1.h0c every step; wr2.hp1 only on push ----
    float fr[4][2];
#pragma unroll
    for (int b = 0; b < 4; ++b) {
      const unsigned* cb = &h0c[b * 144 + kq * 16 + ((kq >> 1) << 2)];
      const uint4 c0 = *(const uint4*)(cb + 0);
      const uint4 c1 = *(const uint4*)(cb + 4);
      const uint4 c2v = *(const uint4*)(cb + 8);
      const uint4 c3 = *(const uint4*)(cb + 12);
      const unsigned hc[16] = {c0.x, c0.y, c0.z, c0.w, c1.x, c1.y, c1.z, c1.w,
                               c2v.x, c2v.y, c2v.z, c2v.w, c3.x, c3.y, c3.z, c3.w};
      float s0 = 0.f, s1 = 0.f;
#pragma unroll
      for (int i = 0; i < 16; ++i) {
        s0 = dot2acc(wr1[i], hc[i], s0);
        s1 = dot2acc(wr1[16 + i], hc[i], s1);
      }
      if (t > 0 && opsA[(t - 1) * 4 + b]) {        // uniform branch
        const unsigned* qb = &hp1[b * 144 + kq * 16 + ((kq >> 1) << 2)];
        const uint4 q0 = *(const uint4*)(qb + 0);
        const uint4 q1 = *(const uint4*)(qb + 4);
        const uint4 q2 = *(const uint4*)(qb + 8);
        const uint4 q3 = *(const uint4*)(qb + 12);
        const unsigned hq[16] = {q0.x, q0.y, q0.z, q0.w, q1.x, q1.y, q1.z, q1.w,
                                 q2.x, q2.y, q2.z, q2.w, q3.x, q3.y, q3.z, q3.w};
        float t0 = 0.f, t1 = 0.f;
#pragma unroll
        for (int i = 0; i < 16; ++i) {
          t0 = dot2acc(wr2[i], hq[i], t0);
          t1 = dot2acc(wr2[16 + i], hq[i], t1);
        }
#pragma unroll
        for (int m = 1; m <= 4; m <<= 1) {
          t0 += __shfl_xor(t0, m, 64);
          t1 += __shfl_xor(t1, m, 64);
        }
        a1q[b][0] = t0;
        a1q[b][1] = t1;
      }
#pragma unroll
      for (int m = 1; m <= 4; m <<= 1) {
        s0 += __shfl_xor(s0, m, 64);
        s1 += __shfl_xor(s1, m, 64);
      }
      fr[b][0] = s0;
      fr[b][1] = s1;
    }
    if (kq == 0) {
#pragma unroll
      for (int b = 0; b < 4; ++b)
        *(float2*)&gatB[b * 64 + c2 * 2] =
            make_float2(fr[b][0] + a1q[b][0] + bias1r[0],
                        fr[b][1] + a1q[b][1] + bias1r[1]);
    }
    __syncthreads();  // B3: gatB ready

    // ---- cell 1: output + gated tagged publish of h1 ----
    if (tid < 64) {
      const int b = tid >> 4, r = tid & 15;
      const float* gt = &gatB[b * 64];
      const float ig = gt[r],      fg = gt[16 + r];
      const float gg = gt[32 + r], og = gt[48 + r];
      const float c = sigf(fg) * cp1 + sigf(ig) * tanhf(gg);
      const float h = sigf(og) * tanhf(c);
      const int op = opsA[t * 4 + b];
      if (op) cp1 = c;
      out[((size_t)t * BB + bg * 4 + b) * HH + hg * 16 + r] = h;
      const float ho = __shfl_xor(h, 1, 64);
      if (op && !(r & 1)) {  // consumers poll this word only when op=1
        const unsigned long long v =
            (unsigned long long)(unsigned)(t + 1) |
            ((unsigned long long)packh2(h, ho) << 32);
        __hip_atomic_store(
            Hx1 + ((size_t)par * NBG + bg) * 512 + b * 128 + hg * 8 + (r >> 1),
            v, __ATOMIC_RELAXED, __HIP_MEMORY_SCOPE_AGENT);
      }
    }
    // no trailing barrier: gatA/gatB split + B1/B2 of next step cover reuse
  }
}

// ---------------------------------------------------------------------------
extern "C" void kernel_launch(void* const* d_in, const int* in_sizes, int n_in,
                              void* d_out, int out_size, void* d_ws, size_t ws_size,
                              hipStream_t stream) {
  const float* x    = (const float*)d_in[0];
  const int*   ops  = (const int*)d_in[1];
  const float* W_ih = (const float*)d_in[2];
  const float* W_hh = (const float*)d_in[3];
  const float* b_ih = (const float*)d_in[4];
  const float* b_hh = (const float*)d_in[5];
  float* out = (float*)d_out;
  float* ws  = (float*)d_ws;

  xg_gemm<<<dim3(64, 8), 256, 0, stream>>>(x, W_ih, b_ih, ws);
  seq9<<<512, BLK, 0, stream>>>(W_ih, W_hh, b_ih, b_hh, ops, ws, out);
}

// Round 8
// 487.534 us; speedup vs baseline: 1.7860x; 1.0005x over previous
//
#include <hip/hip_runtime.h>
#include <hip/hip_fp16.h>
#include <cstddef>

// StackLSTM: T=64, B=128, H=256, L=2.  ops∈{0,1} => stack never pops:
// top-of-stack = h(last push step), maintained by gated update.
//
// Round-15 == Round-14 resubmitted verbatim (r14 bench died in infra:
// "container failed twice", no kernel evidence; source has no new hang
// paths — xg_gemm is spin-free, seq9 byte-identical to 3 passing runs).
//  * xg_gemm register-pressure fix under test: no cross-slab prefetch
//    arrays (staging reuses 16 regs), K-slab 32 -> 64 (barriers 16 -> 8,
//    LDS 67.6KB, still 2 blocks/CU). Peak pressure ~105 VGPR -> no spills.
//  * seq9 VERBATIM (reproduced 385us across r2/r13).
#define TT 64
#define BB 128
#define HH 256
#define G4 1024
#define BLK 256
#define NBG 32

// ws float-slot offsets
#define OFF_HX0 0u         // u64 [2 par][32 bg][4 b][128 k2] = 65,536 floats
#define OFF_HX1 65536u     // same
#define OFF_XG  131072u    // [64 t][16 hg][128 b][64 lc] fp32 = 8,388,608
// total 8,519,680 floats = 34.1 MB (< proven 35.1 MB budget)

__device__ __forceinline__ float sigf(float x) { return 1.0f / (1.0f + expf(-x)); }

typedef _Float16 h2v __attribute__((ext_vector_type(2)));

__device__ __forceinline__ float dot2acc(unsigned w, unsigned h, float acc) {
#if __has_builtin(__builtin_amdgcn_fdot2)
  return __builtin_amdgcn_fdot2(__builtin_bit_cast(h2v, w),
                                __builtin_bit_cast(h2v, h), acc, false);
#else
  __half2 wv = *(__half2*)&w, hv = *(__half2*)&h;
  float2 wf = __half22float2(wv), hf = __half22float2(hv);
  return fmaf(wf.x, hf.x, fmaf(wf.y, hf.y, acc));
#endif
}

__device__ __forceinline__ unsigned packh2(float e, float o) {
  return (unsigned)__half_as_ushort(__float2half(e)) |
         ((unsigned)__half_as_ushort(__float2half(o)) << 16);
}

// swizzled word offset in the [4][144] h-buffers: row kq (16 words) staggered
// by (kq>>1)*4 words so the 8 row starts hit banks {0,16,4,20,8,24,12,28}.
__device__ __forceinline__ int hsw(int b, int k2) {
  return b * 144 + k2 + ((k2 >> 5) << 2);
}

// ---------------------------------------------------------------------------
// xg_gemm: Xg[t][hg][b][lc] = x[t,b,:] @ W_ih0[g,:] + b_ih0[g]   (fp32 exact)
// C[m=t*128+b][g], M=8192, N=1024, K=256.  128x128 tile, 8x8 per thread,
// K-slab 64, no prefetch arrays (register-pressure bound at (256,2)).
// g mapping: hg=(g>>4)&15, lc=((g>>8)<<4)|(g&15)  (matches seq9's reader).
// ---------------------------------------------------------------------------
__global__ void __launch_bounds__(256, 2)
xg_gemm(const float* __restrict__ X,      // [8192][256] (x viewed flat)
        const float* __restrict__ W,      // [1024][256] = W_ih[0]
        const float* __restrict__ bias,   // b_ih layer 0 (first 1024)
        float* __restrict__ ws) {
  float* __restrict__ Xg = ws + OFF_XG;
  const int m0 = blockIdx.x * 128;      // 64 row tiles (t = blockIdx.x)
  const int n0 = blockIdx.y * 128;      // 8 col tiles
  const int tid = threadIdx.x;
  const int tx = tid & 15, ty = tid >> 4;

  __shared__ __align__(16) float Xs[64][132];   // [k][row], +4 pad
  __shared__ __align__(16) float Wn[64][132];   // [k][col], +4 pad

  // staging: thread owns row lr, k-halves lk..lk+32 within the 64-k slab
  const int lr = tid >> 1, lk = (tid & 1) * 32;
  const float* xrow = X + (size_t)(m0 + lr) * HH + lk;
  const float* wrow = W + (size_t)(n0 + lr) * HH + lk;

  float acc[8][8];
#pragma unroll
  for (int i = 0; i < 8; ++i)
#pragma unroll
    for (int j = 0; j < 8; ++j) acc[i][j] = 0.f;

  for (int ks = 0; ks < 4; ++ks) {
    // ---- stage slab (transposed, scalar writes; 16 regs reused) ----
    {
      const float* xp = xrow + ks * 64;
      const float* wp = wrow + ks * 64;
      float4 v[4];
#pragma unroll
      for (int q = 0; q < 4; ++q) v[q] = *(const float4*)(xp + q * 4);
#pragma unroll
      for (int q = 0; q < 4; ++q) {
        Xs[lk + q * 4 + 0][lr] = v[q].x;
        Xs[lk + q * 4 + 1][lr] = v[q].y;
        Xs[lk + q * 4 + 2][lr] = v[q].z;
        Xs[lk + q * 4 + 3][lr] = v[q].w;
      }
#pragma unroll
      for (int q = 0; q < 4; ++q) v[q] = *(const float4*)(xp + 16 + q * 4);
#pragma unroll
      for (int q = 0; q < 4; ++q) {
        Xs[lk + 16 + q * 4 + 0][lr] = v[q].x;
        Xs[lk + 16 + q * 4 + 1][lr] = v[q].y;
        Xs[lk + 16 + q * 4 + 2][lr] = v[q].z;
        Xs[lk + 16 + q * 4 + 3][lr] = v[q].w;
      }
#pragma unroll
      for (int q = 0; q < 4; ++q) v[q] = *(const float4*)(wp + q * 4);
#pragma unroll
      for (int q = 0; q < 4; ++q) {
        Wn[lk + q * 4 + 0][lr] = v[q].x;
        Wn[lk + q * 4 + 1][lr] = v[q].y;
        Wn[lk + q * 4 + 2][lr] = v[q].z;
        Wn[lk + q * 4 + 3][lr] = v[q].w;
      }
#pragma unroll
      for (int q = 0; q < 4; ++q) v[q] = *(const float4*)(wp + 16 + q * 4);
#pragma unroll
      for (int q = 0; q < 4; ++q) {
        Wn[lk + 16 + q * 4 + 0][lr] = v[q].x;
        Wn[lk + 16 + q * 4 + 1][lr] = v[q].y;
        Wn[lk + 16 + q * 4 + 2][lr] = v[q].z;
        Wn[lk + 16 + q * 4 + 3][lr] = v[q].w;
      }
    }
    __syncthreads();

    // ---- compute 64 k (rows: 4-way broadcast; cols: 2-way = free) ----
#pragma unroll 8
    for (int k = 0; k < 64; ++k) {
      const float4 a0 = *(const float4*)&Xs[k][ty * 8];
      const float4 a1 = *(const float4*)&Xs[k][ty * 8 + 4];
      const float4 b0 = *(const float4*)&Wn[k][tx * 4];
      const float4 b1 = *(const float4*)&Wn[k][64 + tx * 4];
      const float ar[8] = {a0.x, a0.y, a0.z, a0.w, a1.x, a1.y, a1.z, a1.w};
      const float br[8] = {b0.x, b0.y, b0.z, b0.w, b1.x, b1.y, b1.z, b1.w};
#pragma unroll
      for (int i = 0; i < 8; ++i)
#pragma unroll
        for (int j = 0; j < 8; ++j) acc[i][j] = fmaf(ar[i], br[j], acc[i][j]);
    }
    __syncthreads();
  }

  // epilogue: +bias, scatter to seq9's [t][hg][b][lc] layout (float4 runs)
  const int t = m0 >> 7;
#pragma unroll
  for (int h = 0; h < 2; ++h) {
    const int base = n0 + h * 64 + tx * 4;            // global col of 4-run
    const int hg = (base >> 4) & 15;
    const int lc = ((base >> 8) << 4) | (base & 15);
    const float4 bv = *(const float4*)(bias + base);
#pragma unroll
    for (int i = 0; i < 8; ++i) {
      const int b = ty * 8 + i;
      float4 v;
      v.x = acc[i][h * 4 + 0] + bv.x;
      v.y = acc[i][h * 4 + 1] + bv.y;
      v.z = acc[i][h * 4 + 2] + bv.z;
      v.w = acc[i][h * 4 + 3] + bv.w;
      *(float4*)&Xg[(((size_t)t * 16 + hg) * 128 + b) * 64 + lc] = v;
    }
  }
}

// ---------------------------------------------------------------------------
// Sequential recurrence: register weights + tagged dataflow exchange.
// VERBATIM the 385us seq9 (round-13 == round-2 + ws offsets).
// ---------------------------------------------------------------------------
__global__ void __launch_bounds__(BLK, 2)
seq9(const float* __restrict__ W_ih,
     const float* __restrict__ W_hh,
     const float* __restrict__ b_ih,
     const float* __restrict__ b_hh,
     const int* __restrict__ ops,
     float* __restrict__ ws,
     float* __restrict__ out) {
  const int bg = blockIdx.x & 31;     // batch group (4 b); group = same bg
  const int hg = blockIdx.x >> 5;     // 0..15
  const int tid = threadIdx.x;
  const int kq = tid & 7;             // k-slice: k2 in [kq*16, kq*16+16)
  const int c2 = tid >> 3;            // 0..31: cols {c2*2, c2*2+1}

  __shared__ __align__(16) float XgL[TT * 256];   // 64 KB [t][b][lc]
  __shared__ __align__(16) unsigned hp0[4 * 144]; // swizzled gated h0 (f16x2)
  __shared__ __align__(16) unsigned hp1[4 * 144]; // swizzled gated h1
  __shared__ __align__(16) unsigned h0c[4 * 144]; // swizzled raw h0(t)
  __shared__ float gatA[256];         // [4 b][64 lc] layer-0 gates
  __shared__ float gatB[256];         // layer-1 gates
  __shared__ int opsA[TT * 4];        // [t][b]

  // ---- prologue: weights -> VGPRs (f16 pairs), Xg slice -> LDS ----
  unsigned wr0[32], wr1[32], wr2[32];
  {
    const float* s0 = W_hh;                       // W_hh[0]
    const float* s1 = W_ih + (size_t)G4 * HH;     // W_ih[1]
    const float* s2 = W_hh + (size_t)G4 * HH;     // W_hh[1]
#pragma unroll
    for (int j = 0; j < 2; ++j) {
      const int lc = c2 * 2 + j;
      const int g = ((lc >> 4) << 8) + hg * 16 + (lc & 15);
      const float* p0 = s0 + (size_t)g * HH + kq * 32;
      const float* p1 = s1 + (size_t)g * HH + kq * 32;
      const float* p2 = s2 + (size_t)g * HH + kq * 32;
#pragma unroll
      for (int i = 0; i < 16; ++i) {
        wr0[j * 16 + i] = packh2(p0[2 * i], p0[2 * i + 1]);
        wr1[j * 16 + i] = packh2(p1[2 * i], p1[2 * i + 1]);
        wr2[j * 16 + i] = packh2(p2[2 * i], p2[2 * i + 1]);
      }
    }
  }
  float bias0r[2], bias1r[2];
#pragma unroll
  for (int j = 0; j < 2; ++j) {
    const int lc = c2 * 2 + j;
    const int g = ((lc >> 4) << 8) + hg * 16 + (lc & 15);
    bias0r[j] = b_hh[g];                           // b_ih0 folded into Xg
    bias1r[j] = b_ih[G4 + g] + b_hh[G4 + g];
  }
  for (int i = tid; i < TT * 64; i += BLK) {       // 4096 float4
    const int t = i >> 6, r = i & 63;
    ((float4*)XgL)[i] = *(const float4*)(
        ws + OFF_XG + (((size_t)t * 16 + hg) * 128 + bg * 4) * 64 + r * 4);
  }
  for (int i = tid; i < TT * 4; i += BLK)
    opsA[i] = ops[(i >> 2) * BB + bg * 4 + (i & 3)];
  for (int i = tid; i < 4 * 144; i += BLK) { hp0[i] = 0u; hp1[i] = 0u; }

  unsigned long long* __restrict__ Hx0 = (unsigned long long*)(ws + OFF_HX0);
  unsigned long long* __restrict__ Hx1 = (unsigned long long*)(ws + OFF_HX1);
  float cp0 = 0.f, cp1 = 0.f;         // cell state, held by tid<64
  // push-gated caches: post-butterfly sums (valid in ALL lanes)
  float a0r[4][2] = {{0.f, 0.f}, {0.f, 0.f}, {0.f, 0.f}, {0.f, 0.f}};
  float a1q[4][2] = {{0.f, 0.f}, {0.f, 0.f}, {0.f, 0.f}, {0.f, 0.f}};
  __syncthreads();

  for (int t = 0; t < TT; ++t) {
    const int par = t & 1;

    // ---- layer-0 dots: recompute wr0.hp0 only for b pushed at t-1 ----
#pragma unroll
    for (int b = 0; b < 4; ++b) {
      if (t > 0 && opsA[(t - 1) * 4 + b]) {        // uniform branch
        const unsigned* hb = &hp0[b * 144 + kq * 16 + ((kq >> 1) << 2)];
        const uint4 x0 = *(const uint4*)(hb + 0);
        const uint4 x1 = *(const uint4*)(hb + 4);
        const uint4 x2 = *(const uint4*)(hb + 8);
        const uint4 x3 = *(const uint4*)(hb + 12);
        const unsigned hh[16] = {x0.x, x0.y, x0.z, x0.w, x1.x, x1.y, x1.z, x1.w,
                                 x2.x, x2.y, x2.z, x2.w, x3.x, x3.y, x3.z, x3.w};
        float s0 = 0.f, s1 = 0.f;
#pragma unroll
        for (int i = 0; i < 16; ++i) {
          s0 = dot2acc(wr0[i], hh[i], s0);
          s1 = dot2acc(wr0[16 + i], hh[i], s1);
        }
#pragma unroll
        for (int m = 1; m <= 4; m <<= 1) {
          s0 += __shfl_xor(s0, m, 64);
          s1 += __shfl_xor(s1, m, 64);
        }
        a0r[b][0] = s0;
        a0r[b][1] = s1;
      }
    }
    if (kq == 0) {
#pragma unroll
      for (int b = 0; b < 4; ++b)
        *(float2*)&gatA[b * 64 + c2 * 2] =
            make_float2(a0r[b][0] + bias0r[0], a0r[b][1] + bias0r[1]);
    }
    __syncthreads();  // B1: gatA ready; also orders hp0 reads before merge

    // ---- cell 0 + tagged publish of h0 (8-B relaxed atomics) ----
    if (tid < 64) {
      const int b = tid >> 4, r = tid & 15;
      const float* xg = &XgL[t * 256 + b * 64];
      const float* gt = &gatA[b * 64];
      const float ig = gt[r] + xg[r],           fg = gt[16 + r] + xg[16 + r];
      const float gg = gt[32 + r] + xg[32 + r], og = gt[48 + r] + xg[48 + r];
      const float c = sigf(fg) * cp0 + sigf(ig) * tanhf(gg);
      const float h = sigf(og) * tanhf(c);
      if (opsA[t * 4 + b]) cp0 = c;
      const float ho = __shfl_xor(h, 1, 64);  // pair partner (wave 0 full)
      if (!(r & 1)) {
        const unsigned long long v =
            (unsigned long long)(unsigned)(t + 1) |
            ((unsigned long long)packh2(h, ho) << 32);
        __hip_atomic_store(
            Hx0 + ((size_t)par * NBG + bg) * 512 + b * 128 + hg * 8 + (r >> 1),
            v, __ATOMIC_RELAXED, __HIP_MEMORY_SCOPE_AGENT);
      }
    }
    // no sync: merge polls below self-synchronize on the tags

    // ---- merge: ONE combined spin over all needed words (overlapped RTs) --
    {
      const unsigned long long* s0 = Hx0 + ((size_t)par * NBG + bg) * 512;
      const unsigned long long* s1 = Hx1 + ((size_t)(par ^ 1) * NBG + bg) * 512;
      const unsigned tagA = (unsigned)(t + 1);
      const unsigned tagB = (unsigned)t;
      const int idx1 = tid + 256;
      const int b0 = tid >> 7, k20 = tid & 127;
      const int b1 = idx1 >> 7, k21 = idx1 & 127;
      const bool need1a = (t > 0) && (opsA[(t - 1) * 4 + b0] != 0);
      const bool need1b = (t > 0) && (opsA[(t - 1) * 4 + b1] != 0);
      unsigned long long v0 = 0, v1 = 0, w0 = 0, w1 = 0;
      bool d0 = false, d1 = false, e0 = !need1a, e1 = !need1b;
      int spins = 0;
      for (;;) {
        // issue ALL unresolved loads back-to-back so their latencies overlap
        if (!d0) v0 = __hip_atomic_load(s0 + tid, __ATOMIC_RELAXED,
                                        __HIP_MEMORY_SCOPE_AGENT);
        if (!d1) v1 = __hip_atomic_load(s0 + idx1, __ATOMIC_RELAXED,
                                        __HIP_MEMORY_SCOPE_AGENT);
        if (!e0) w0 = __hip_atomic_load(s1 + tid, __ATOMIC_RELAXED,
                                        __HIP_MEMORY_SCOPE_AGENT);
        if (!e1) w1 = __hip_atomic_load(s1 + idx1, __ATOMIC_RELAXED,
                                        __HIP_MEMORY_SCOPE_AGENT);
        d0 = d0 || ((unsigned)v0 == tagA);
        d1 = d1 || ((unsigned)v1 == tagA);
        e0 = e0 || ((unsigned)w0 == tagB);
        e1 = e1 || ((unsigned)w1 == tagB);
        if (d0 && d1 && e0 && e1) break;
        if (++spins > (1 << 18)) break;  // fail loudly instead of hanging
        if (spins > 2) __builtin_amdgcn_s_sleep(1);
      }
      const unsigned p0 = (unsigned)(v0 >> 32), p1 = (unsigned)(v1 >> 32);
      const int sw0 = hsw(b0, k20), sw1 = hsw(b1, k21);
      h0c[sw0] = p0;
      h0c[sw1] = p1;
      if (opsA[t * 4 + b0]) hp0[sw0] = p0;
      if (opsA[t * 4 + b1]) hp0[sw1] = p1;
      if (need1a) hp1[sw0] = (unsigned)(w0 >> 32);
      if (need1b) hp1[sw1] = (unsigned)(w1 >> 32);
    }
    __syncthreads();  // B2: h0c/hp0/hp1 ready for layer-1 reads

    // ---- layer-1 dots: wr1.h0c every step; wr2.hp1 only on push ----
    float fr[4][2];
#pragma unroll
    for (int b = 0; b < 4; ++b) {
      const unsigned* cb = &h0c[b * 144 + kq * 16 + ((kq >> 1) << 2)];
      const uint4 c0 = *(const uint4*)(cb + 0);
      const uint4 c1 = *(const uint4*)(cb + 4);
      const uint4 c2v = *(const uint4*)(cb + 8);
      const uint4 c3 = *(const uint4*)(cb + 12);
      const unsigned hc[16] = {c0.x, c0.y, c0.z, c0.w, c1.x, c1.y, c1.z, c1.w,
                               c2v.x, c2v.y, c2v.z, c2v.w, c3.x, c3.y, c3.z, c3.w};
      float s0 = 0.f, s1 = 0.f;
#pragma unroll
      for (int i = 0; i < 16; ++i) {
        s0 = dot2acc(wr1[i], hc[i], s0);
        s1 = dot2acc(wr1[16 + i], hc[i], s1);
      }
      if (t > 0 && opsA[(t - 1) * 4 + b]) {        // uniform branch
        const unsigned* qb = &hp1[b * 144 + kq * 16 + ((kq >> 1) << 2)];
        const uint4 q0 = *(const uint4*)(qb + 0);
        const uint4 q1 = *(const uint4*)(qb + 4);
        const uint4 q2 = *(const uint4*)(qb + 8);
        const uint4 q3 = *(const uint4*)(qb + 12);
        const unsigned hq[16] = {q0.x, q0.y, q0.z, q0.w, q1.x, q1.y, q1.z, q1.w,
                                 q2.x, q2.y, q2.z, q2.w, q3.x, q3.y, q3.z, q3.w};
        float t0 = 0.f, t1 = 0.f;
#pragma unroll
        for (int i = 0; i < 16; ++i) {
          t0 = dot2acc(wr2[i], hq[i], t0);
          t1 = dot2acc(wr2[16 + i], hq[i], t1);
        }
#pragma unroll
        for (int m = 1; m <= 4; m <<= 1) {
          t0 += __shfl_xor(t0, m, 64);
          t1 += __shfl_xor(t1, m, 64);
        }
        a1q[b][0] = t0;
        a1q[b][1] = t1;
      }
#pragma unroll
      for (int m = 1; m <= 4; m <<= 1) {
        s0 += __shfl_xor(s0, m, 64);
        s1 += __shfl_xor(s1, m, 64);
      }
      fr[b][0] = s0;
      fr[b][1] = s1;
    }
    if (kq == 0) {
#pragma unroll
      for (int b = 0; b < 4; ++b)
        *(float2*)&gatB[b * 64 + c2 * 2] =
            make_float2(fr[b][0] + a1q[b][0] + bias1r[0],
                        fr[b][1] + a1q[b][1] + bias1r[1]);
    }
    __syncthreads();  // B3: gatB ready

    // ---- cell 1: output + gated tagged publish of h1 ----
    if (tid < 64) {
      const int b = tid >> 4, r = tid & 15;
      const float* gt = &gatB[b * 64];
      const float ig = gt[r],      fg = gt[16 + r];
      const float gg = gt[32 + r], og = gt[48 + r];
      const float c = sigf(fg) * cp1 + sigf(ig) * tanhf(gg);
      const float h = sigf(og) * tanhf(c);
      const int op = opsA[t * 4 + b];
      if (op) cp1 = c;
      out[((size_t)t * BB + bg * 4 + b) * HH + hg * 16 + r] = h;
      const float ho = __shfl_xor(h, 1, 64);
      if (op && !(r & 1)) {  // consumers poll this word only when op=1
        const unsigned long long v =
            (unsigned long long)(unsigned)(t + 1) |
            ((unsigned long long)packh2(h, ho) << 32);
        __hip_atomic_store(
            Hx1 + ((size_t)par * NBG + bg) * 512 + b * 128 + hg * 8 + (r >> 1),
            v, __ATOMIC_RELAXED, __HIP_MEMORY_SCOPE_AGENT);
      }
    }
    // no trailing barrier: gatA/gatB split + B1/B2 of next step cover reuse
  }
}

// ---------------------------------------------------------------------------
extern "C" void kernel_launch(void* const* d_in, const int* in_sizes, int n_in,
                              void* d_out, int out_size, void* d_ws, size_t ws_size,
                              hipStream_t stream) {
  const float* x    = (const float*)d_in[0];
  const int*   ops  = (const int*)d_in[1];
  const float* W_ih = (const float*)d_in[2];
  const float* W_hh = (const float*)d_in[3];
  const float* b_ih = (const float*)d_in[4];
  const float* b_hh = (const float*)d_in[5];
  float* out = (float*)d_out;
  float* ws  = (float*)d_ws;

  xg_gemm<<<dim3(64, 8), 256, 0, stream>>>(x, W_ih, b_ih, ws);
  seq9<<<512, BLK, 0, stream>>>(W_ih, W_hh, b_ih, b_hh, ops, ws, out);
}